// Round 1
// baseline (2072.506 us; speedup 1.0000x reference)
//
#include <hip/hip_runtime.h>

#define EMBED 768
#define NH 12
#define HD 64
#define SEQ 4096
#define BATCH 2
#define MROWS (BATCH * SEQ)   // 8192
#define N3E (3 * EMBED)       // 2304

// ---------------------------------------------------------------------------
// Tiled fp32 GEMM: C[M,N] = X[M,K] @ W[K,N] + bias[N]
// 64x64 tile, BK=16, 256 threads, 4x4 micro-tile per thread.
// SCATTER=true: N==2304, split columns t*768 + h*64 + d into q/k/v buffers
// laid out [B,H,S,D]. SCATTER=false: plain row-major [M,N] output.
// ---------------------------------------------------------------------------
template <int N_, int K_, bool SCATTER>
__global__ __launch_bounds__(256) void gemm_kernel(
    const float* __restrict__ X, const float* __restrict__ W,
    const float* __restrict__ bias, float* __restrict__ out0,
    float* __restrict__ out1, float* __restrict__ out2) {
  __shared__ float As[16][68];  // [k][m], pad->aligned float4 reads
  __shared__ float Bs[16][68];  // [k][n]
  const int tid = threadIdx.x;
  const int tx = tid & 15, ty = tid >> 4;
  const int bm = blockIdx.y * 64;
  const int bn = blockIdx.x * 64;

  float acc[4][4] = {};

  for (int k0 = 0; k0 < K_; k0 += 16) {
    // A tile: 64 rows x 16 k.  16 consecutive lanes read 16 consecutive k.
#pragma unroll
    for (int r = 0; r < 4; ++r) {
      int m = (tid >> 4) + r * 16;
      int kk = tid & 15;
      As[kk][m] = X[(size_t)(bm + m) * K_ + k0 + kk];
    }
    // B tile: 16 k x 64 n. 64 consecutive lanes read 64 consecutive n.
#pragma unroll
    for (int r = 0; r < 4; ++r) {
      int kk = (tid >> 6) + r * 4;
      int n = tid & 63;
      Bs[kk][n] = W[(size_t)(k0 + kk) * N_ + bn + n];
    }
    __syncthreads();
#pragma unroll
    for (int kk = 0; kk < 16; ++kk) {
      float a[4], b[4];
#pragma unroll
      for (int i = 0; i < 4; ++i) a[i] = As[kk][ty * 4 + i];
#pragma unroll
      for (int j = 0; j < 4; ++j) b[j] = Bs[kk][tx * 4 + j];
#pragma unroll
      for (int i = 0; i < 4; ++i)
#pragma unroll
        for (int j = 0; j < 4; ++j) acc[i][j] += a[i] * b[j];
    }
    __syncthreads();
  }

#pragma unroll
  for (int i = 0; i < 4; ++i) {
    int m = bm + ty * 4 + i;
#pragma unroll
    for (int j = 0; j < 4; ++j) {
      int n = bn + tx * 4 + j;
      float v = acc[i][j] + bias[n];
      if (SCATTER) {
        int t = n / EMBED;          // 0=q 1=k 2=v
        int rem = n - t * EMBED;
        int h = rem >> 6;
        int d = n & 63;
        int b_ = m >> 12;           // m / SEQ
        int s = m & 4095;
        float* dst = (t == 0) ? out0 : (t == 1) ? out1 : out2;
        dst[(((size_t)(b_ * NH + h)) * SEQ + s) * HD + d] = v;
      } else {
        out0[(size_t)m * N_ + n] = v;
      }
    }
  }
}

// ---------------------------------------------------------------------------
// Causal flash attention, fp32. One block per (q-tile of 64 rows, b*h).
// Q,K stored transposed in LDS ([d][row], pad 65 -> 2-way = free).
// Scores computed as S^T = K.Q^T so P lands in [kr][qr] layout (the
// A-operand layout for PV) with conflict-free, vectorizable writes.
// Online softmax (m, l, alpha per q-row) in LDS.
// ---------------------------------------------------------------------------
__global__ __launch_bounds__(256) void flash_kernel(
    const float* __restrict__ qb, const float* __restrict__ kb,
    const float* __restrict__ vb, float* __restrict__ attn) {
  __shared__ float Qt[64][65];  // [d][qr], pre-scaled by 1/8
  __shared__ float Kt[64][65];  // [d][kr]
  __shared__ float Vs[64][68];  // [kr][d]
  __shared__ float Ss[64][68];  // [kr][qr] : S^T then P^T
  __shared__ float mrow[64], lrow[64], arow[64];
  __shared__ float redmax[4][64], redsum[4][64];

  const int tid = threadIdx.x;
  const int tx = tid & 15, ty = tid >> 4;
  const int qt = blockIdx.x;   // q tile (0..63)
  const int bh = blockIdx.y;   // 0..23

  const size_t base = (size_t)bh * SEQ * HD;
  const float* Qg = qb + base;
  const float* Kg = kb + base;
  const float* Vg = vb + base;

  // Load Q tile (transposed, pre-scaled by 1/sqrt(64))
#pragma unroll
  for (int r = 0; r < 16; ++r) {
    int idx = tid + r * 256;
    int row = idx >> 6, d = idx & 63;
    Qt[d][row] = Qg[(size_t)(qt * 64 + row) * HD + d] * 0.125f;
  }
  if (tid < 64) { mrow[tid] = -1e30f; lrow[tid] = 0.f; }

  float acc[4][4] = {};
  __syncthreads();

  for (int kt = 0; kt <= qt; ++kt) {
    // Load K (transposed) and V tiles
#pragma unroll
    for (int r = 0; r < 16; ++r) {
      int idx = tid + r * 256;
      int row = idx >> 6, d = idx & 63;
      size_t g = (size_t)(kt * 64 + row) * HD + d;
      Kt[d][row] = Kg[g];
      Vs[row][d] = Vg[g];
    }
    __syncthreads();  // [A]

    // S^T micro-tile: st[i][j] = S[qr=tx*4+j][kr=ty*4+i]
    float st[4][4] = {};
#pragma unroll 4
    for (int d = 0; d < 64; ++d) {
      float a[4], b[4];
#pragma unroll
      for (int i = 0; i < 4; ++i) a[i] = Kt[d][ty * 4 + i];
#pragma unroll
      for (int j = 0; j < 4; ++j) b[j] = Qt[d][tx * 4 + j];
#pragma unroll
      for (int i = 0; i < 4; ++i)
#pragma unroll
        for (int j = 0; j < 4; ++j) st[i][j] += a[i] * b[j];
    }
    const bool diag = (kt == qt);
#pragma unroll
    for (int i = 0; i < 4; ++i) {
      int kr = ty * 4 + i;
#pragma unroll
      for (int j = 0; j < 4; ++j) {
        int qr = tx * 4 + j;
        float v = st[i][j];
        if (diag && kr > qr) v = -1e30f;
        Ss[kr][qr] = v;
      }
    }
    __syncthreads();  // [B]

    // Online softmax over kr, per q-row. 4 threads per row.
    const int qr = tid & 63;
    const int p = tid >> 6;
    float pm = -1e30f;
#pragma unroll
    for (int k2 = 0; k2 < 16; ++k2) pm = fmaxf(pm, Ss[p * 16 + k2][qr]);
    redmax[p][qr] = pm;
    float mold = mrow[qr];  // read BEFORE barrier; written only after [C]
    __syncthreads();  // [C]
    float mnew = fmaxf(
        fmaxf(fmaxf(redmax[0][qr], redmax[1][qr]),
              fmaxf(redmax[2][qr], redmax[3][qr])),
        mold);
    if (p == 0) { mrow[qr] = mnew; arow[qr] = __expf(mold - mnew); }
    float ps = 0.f;
#pragma unroll
    for (int k2 = 0; k2 < 16; ++k2) {
      float e = __expf(Ss[p * 16 + k2][qr] - mnew);
      Ss[p * 16 + k2][qr] = e;
      ps += e;
    }
    redsum[p][qr] = ps;
    __syncthreads();  // [E]
    if (p == 0)
      lrow[qr] = lrow[qr] * arow[qr] +
                 (redsum[0][qr] + redsum[1][qr] + redsum[2][qr] + redsum[3][qr]);

    // Rescale accumulator then P^T.V accumulate.
    float al[4];
#pragma unroll
    for (int i = 0; i < 4; ++i) al[i] = arow[ty * 4 + i];
#pragma unroll
    for (int i = 0; i < 4; ++i)
#pragma unroll
      for (int j = 0; j < 4; ++j) acc[i][j] *= al[i];

#pragma unroll 4
    for (int kr = 0; kr < 64; ++kr) {
      float a[4], b[4];
#pragma unroll
      for (int i = 0; i < 4; ++i) a[i] = Ss[kr][ty * 4 + i];
#pragma unroll
      for (int j = 0; j < 4; ++j) b[j] = Vs[kr][tx * 4 + j];
#pragma unroll
      for (int i = 0; i < 4; ++i)
#pragma unroll
        for (int j = 0; j < 4; ++j) acc[i][j] += a[i] * b[j];
    }
    __syncthreads();  // [F]
  }

  // Epilogue: O / l, write to [B,S,E] layout (ready for out-proj GEMM).
  const int b_ = bh / NH, h = bh % NH;
#pragma unroll
  for (int i = 0; i < 4; ++i) {
    int qr = ty * 4 + i;
    float inv = 1.f / lrow[qr];
    int srow = qt * 64 + qr;
#pragma unroll
    for (int j = 0; j < 4; ++j) {
      int d = tx * 4 + j;
      attn[((size_t)(b_ * SEQ + srow)) * EMBED + h * HD + d] = acc[i][j] * inv;
    }
  }
}

extern "C" void kernel_launch(void* const* d_in, const int* in_sizes, int n_in,
                              void* d_out, int out_size, void* d_ws,
                              size_t ws_size, hipStream_t stream) {
  const float* x = (const float*)d_in[0];      // [B,S,E]
  const float* w_qkv = (const float*)d_in[1];  // [E,3E]
  const float* b_qkv = (const float*)d_in[2];  // [3E]
  const float* w_out = (const float*)d_in[3];  // [E,E]
  const float* b_out = (const float*)d_in[4];  // [E]
  float* out = (float*)d_out;                  // [B,S,E]

  const size_t per = (size_t)BATCH * NH * SEQ * HD;  // 6291456
  float* q_buf = (float*)d_ws;
  float* k_buf = q_buf + per;
  float* v_buf = k_buf + per;
  float* attn_buf = v_buf + per;

  dim3 g1(N3E / 64, MROWS / 64);  // (36,128)
  gemm_kernel<N3E, EMBED, true>
      <<<g1, 256, 0, stream>>>(x, w_qkv, b_qkv, q_buf, k_buf, v_buf);

  dim3 g2(SEQ / 64, BATCH * NH);  // (64,24)
  flash_kernel<<<g2, 256, 0, stream>>>(q_buf, k_buf, v_buf, attn_buf);

  dim3 g3(EMBED / 64, MROWS / 64);  // (12,128)
  gemm_kernel<EMBED, EMBED, false>
      <<<g3, 256, 0, stream>>>(attn_buf, w_out, b_out, out, nullptr, nullptr);
}

// Round 2
// 927.140 us; speedup vs baseline: 2.2354x; 2.2354x over previous
//
#include <hip/hip_runtime.h>

#define EMBED 768
#define NH 12
#define HD 64
#define SEQ 4096
#define BATCH 2
#define MROWS (BATCH * SEQ)   // 8192
#define N3E (3 * EMBED)       // 2304

typedef short bf16x8 __attribute__((ext_vector_type(8)));  // 8 bf16 = 4 VGPRs
typedef float fx4 __attribute__((ext_vector_type(4)));     // MFMA C/D

// fp32 -> bf16 round-to-nearest-even (bit trick; NaN irrelevant here)
__device__ inline unsigned short f2bf(float f) {
  union { float f; unsigned int u; } x; x.f = f;
  unsigned int r = x.u + 0x7fffu + ((x.u >> 16) & 1u);
  return (unsigned short)(r >> 16);
}

// ---------------------------------------------------------------------------
// Tiled fp32 GEMM: C[M,N] = X[M,K] @ W[K,N] + bias[N]
// SCATTER=true: N==2304, split cols into bf16 q/k/v buffers [B,H,S,D];
//               q pre-scaled by 1/sqrt(HD).
// SCATTER=false: plain fp32 row-major [M,N] output.
// ---------------------------------------------------------------------------
template <int N_, int K_, bool SCATTER>
__global__ __launch_bounds__(256) void gemm_kernel(
    const float* __restrict__ X, const float* __restrict__ W,
    const float* __restrict__ bias, float* __restrict__ outF,
    unsigned short* __restrict__ oq, unsigned short* __restrict__ ok,
    unsigned short* __restrict__ ov) {
  __shared__ float As[16][68];  // [k][m]
  __shared__ float Bs[16][68];  // [k][n]
  const int tid = threadIdx.x;
  const int tx = tid & 15, ty = tid >> 4;
  const int bm = blockIdx.y * 64;
  const int bn = blockIdx.x * 64;

  float acc[4][4] = {};

  for (int k0 = 0; k0 < K_; k0 += 16) {
#pragma unroll
    for (int r = 0; r < 4; ++r) {
      int m = (tid >> 4) + r * 16;
      int kk = tid & 15;
      As[kk][m] = X[(size_t)(bm + m) * K_ + k0 + kk];
    }
#pragma unroll
    for (int r = 0; r < 4; ++r) {
      int kk = (tid >> 6) + r * 4;
      int n = tid & 63;
      Bs[kk][n] = W[(size_t)(k0 + kk) * N_ + bn + n];
    }
    __syncthreads();
#pragma unroll
    for (int kk = 0; kk < 16; ++kk) {
      float a[4], b[4];
#pragma unroll
      for (int i = 0; i < 4; ++i) a[i] = As[kk][ty * 4 + i];
#pragma unroll
      for (int j = 0; j < 4; ++j) b[j] = Bs[kk][tx * 4 + j];
#pragma unroll
      for (int i = 0; i < 4; ++i)
#pragma unroll
        for (int j = 0; j < 4; ++j) acc[i][j] += a[i] * b[j];
    }
    __syncthreads();
  }

#pragma unroll
  for (int i = 0; i < 4; ++i) {
    int m = bm + ty * 4 + i;
#pragma unroll
    for (int j = 0; j < 4; ++j) {
      int n = bn + tx * 4 + j;
      float v = acc[i][j] + bias[n];
      if (SCATTER) {
        int t = n / EMBED;  // 0=q 1=k 2=v
        int rem = n - t * EMBED;
        int h = rem >> 6;
        int d = n & 63;
        int b_ = m >> 12;
        int s = m & 4095;
        unsigned short* dst = (t == 0) ? oq : (t == 1) ? ok : ov;
        if (t == 0) v *= 0.125f;  // 1/sqrt(HD) folded into Q
        dst[(((size_t)(b_ * NH + h)) * SEQ + s) * HD + d] = f2bf(v);
      } else {
        outF[(size_t)m * N_ + n] = v;
      }
    }
  }
}

// ---------------------------------------------------------------------------
// Causal flash attention, bf16 MFMA (16x16x32), fp32 accumulate.
// Block = 4 waves, 64 q-rows; wave w owns q-row slab [w*16, w*16+16).
// S^ tile in C/D layout (row=quad*4+reg, col=lane&15); softmax fully in
// registers (butterfly over the 16-lane group); P -> LDS -> A-fragment
// (wave-private rows, no extra barrier); PV accumulates O in C/D layout.
// K in LDS as [kr][d], V transposed [d][kr], P [qr][kr]; all pad +8 bf16
// so rows stay 16B-aligned for ds_read_b128.
// ---------------------------------------------------------------------------
__global__ __launch_bounds__(256) void flash_mfma(
    const unsigned short* __restrict__ qb, const unsigned short* __restrict__ kb,
    const unsigned short* __restrict__ vb, float* __restrict__ attn) {
  __shared__ unsigned short Ks[64][72];
  __shared__ unsigned short Vt[64][72];
  __shared__ unsigned short Ps[64][72];

  const int tid = threadIdx.x;
  const int w = tid >> 6;
  const int lane = tid & 63;
  const int quad = lane >> 4;
  const int ln = lane & 15;

  const int qt = (int)gridDim.x - 1 - (int)blockIdx.x;  // big blocks first
  const int bh = blockIdx.y;
  const size_t base = (size_t)bh * SEQ * HD;
  const unsigned short* Qg = qb + base;
  const unsigned short* Kg = kb + base;
  const unsigned short* Vg = vb + base;

  // Q A-fragments, held in registers for all kt iterations.
  bf16x8 qf0, qf1;
  {
    const unsigned short* qrow = Qg + (size_t)(qt * 64 + w * 16 + ln) * HD;
    qf0 = *(const bf16x8*)(qrow + quad * 8);
    qf1 = *(const bf16x8*)(qrow + 32 + quad * 8);
  }

  fx4 oacc[4] = {};  // O[w*16+quad*4+r][t*16+ln], t = d-tile
  float mrow[4], lrow[4];
#pragma unroll
  for (int r = 0; r < 4; ++r) { mrow[r] = -1e30f; lrow[r] = 0.f; }

  for (int kt = 0; kt <= qt; ++kt) {
    __syncthreads();  // protect previous iteration's LDS reads
    // ---- stage K tile: [kr][d], coalesced 16B loads ----
#pragma unroll
    for (int r = 0; r < 2; ++r) {
      int c = tid + r * 256;
      int kr = c >> 3, d0 = (c & 7) * 8;
      *(bf16x8*)&Ks[kr][d0] =
          *(const bf16x8*)(Kg + (size_t)(kt * 64 + kr) * HD + d0);
    }
    // ---- stage V transposed: Vt[d][kr] ----
    {
      int kr = lane, d0 = w * 16;
      const unsigned short* vrow = Vg + (size_t)(kt * 64 + kr) * HD + d0;
      bf16x8 v0 = *(const bf16x8*)(vrow);
      bf16x8 v1 = *(const bf16x8*)(vrow + 8);
#pragma unroll
      for (int j = 0; j < 8; ++j) Vt[d0 + j][kr] = (unsigned short)v0[j];
#pragma unroll
      for (int j = 0; j < 8; ++j) Vt[d0 + 8 + j][kr] = (unsigned short)v1[j];
    }
    __syncthreads();

    const bool diag = (kt == qt);
    // ---- S = Q.K^T, wave slab 16 x 64 ----
    float sv[4][4];  // [kr-tile t][reg]
#pragma unroll
    for (int t = 0; t < 4; ++t) {
      if (diag && t > w) {
#pragma unroll
        for (int r = 0; r < 4; ++r) sv[t][r] = -1e30f;
      } else {
        fx4 c = {};
        bf16x8 kf0 = *(const bf16x8*)&Ks[t * 16 + ln][quad * 8];
        bf16x8 kf1 = *(const bf16x8*)&Ks[t * 16 + ln][32 + quad * 8];
        c = __builtin_amdgcn_mfma_f32_16x16x32_bf16(qf0, kf0, c, 0, 0, 0);
        c = __builtin_amdgcn_mfma_f32_16x16x32_bf16(qf1, kf1, c, 0, 0, 0);
#pragma unroll
        for (int r = 0; r < 4; ++r) sv[t][r] = c[r];
        if (diag && t == w) {
#pragma unroll
          for (int r = 0; r < 4; ++r)
            if (ln > quad * 4 + r) sv[t][r] = -1e30f;
        }
      }
    }

    // ---- online softmax, in-register (rows = quad*4+r of the slab) ----
    float mnew[4], alpha[4];
#pragma unroll
    for (int r = 0; r < 4; ++r) {
      float rm = fmaxf(fmaxf(sv[0][r], sv[1][r]), fmaxf(sv[2][r], sv[3][r]));
      rm = fmaxf(rm, __shfl_xor(rm, 1));
      rm = fmaxf(rm, __shfl_xor(rm, 2));
      rm = fmaxf(rm, __shfl_xor(rm, 4));
      rm = fmaxf(rm, __shfl_xor(rm, 8));
      mnew[r] = fmaxf(mrow[r], rm);
      alpha[r] = __expf(mrow[r] - mnew[r]);
      mrow[r] = mnew[r];
    }
    float pv[4][4];
#pragma unroll
    for (int r = 0; r < 4; ++r) {
      float s0 = 0.f;
#pragma unroll
      for (int t = 0; t < 4; ++t) {
        float e = __expf(sv[t][r] - mnew[r]);
        pv[t][r] = e;
        s0 += e;
      }
      s0 += __shfl_xor(s0, 1);
      s0 += __shfl_xor(s0, 2);
      s0 += __shfl_xor(s0, 4);
      s0 += __shfl_xor(s0, 8);
      lrow[r] = lrow[r] * alpha[r] + s0;
    }
    // ---- P -> LDS (wave-private rows; no barrier needed) ----
#pragma unroll
    for (int t = 0; t < 4; ++t)
#pragma unroll
      for (int r = 0; r < 4; ++r)
        Ps[w * 16 + quad * 4 + r][t * 16 + ln] = f2bf(pv[t][r]);
    // ---- rescale O ----
#pragma unroll
    for (int t = 0; t < 4; ++t)
#pragma unroll
      for (int r = 0; r < 4; ++r) oacc[t][r] *= alpha[r];
    // ---- O += P.V ----
#pragma unroll
    for (int kb2 = 0; kb2 < 2; ++kb2) {
      bf16x8 pf = *(const bf16x8*)&Ps[w * 16 + ln][kb2 * 32 + quad * 8];
#pragma unroll
      for (int t = 0; t < 4; ++t) {
        bf16x8 vf = *(const bf16x8*)&Vt[t * 16 + ln][kb2 * 32 + quad * 8];
        oacc[t] = __builtin_amdgcn_mfma_f32_16x16x32_bf16(pf, vf, oacc[t], 0, 0, 0);
      }
    }
  }

  // ---- epilogue: O/l -> attn [B,S,E] fp32 ----
  const int b_ = bh / NH, h = bh % NH;
#pragma unroll
  for (int r = 0; r < 4; ++r) {
    float inv = 1.f / lrow[r];
    int srow = qt * 64 + w * 16 + quad * 4 + r;
    float* orow = attn + ((size_t)(b_ * SEQ + srow)) * EMBED + h * HD;
#pragma unroll
    for (int t = 0; t < 4; ++t) orow[t * 16 + ln] = oacc[t][r] * inv;
  }
}

extern "C" void kernel_launch(void* const* d_in, const int* in_sizes, int n_in,
                              void* d_out, int out_size, void* d_ws,
                              size_t ws_size, hipStream_t stream) {
  const float* x = (const float*)d_in[0];      // [B,S,E]
  const float* w_qkv = (const float*)d_in[1];  // [E,3E]
  const float* b_qkv = (const float*)d_in[2];  // [3E]
  const float* w_out = (const float*)d_in[3];  // [E,E]
  const float* b_out = (const float*)d_in[4];  // [E]
  float* out = (float*)d_out;                  // [B,S,E]

  const size_t per = (size_t)BATCH * NH * SEQ * HD;  // 6291456
  unsigned short* q_buf = (unsigned short*)d_ws;
  unsigned short* k_buf = q_buf + per;
  unsigned short* v_buf = k_buf + per;
  float* attn_buf = (float*)(v_buf + per);  // byte offset 37748736, 16B-aligned

  dim3 g1(N3E / 64, MROWS / 64);  // (36,128)
  gemm_kernel<N3E, EMBED, true>
      <<<g1, 256, 0, stream>>>(x, w_qkv, b_qkv, nullptr, q_buf, k_buf, v_buf);

  dim3 g2(SEQ / 64, BATCH * NH);  // (64,24)
  flash_mfma<<<g2, 256, 0, stream>>>(q_buf, k_buf, v_buf, attn_buf);

  dim3 g3(EMBED / 64, MROWS / 64);  // (12,128)
  gemm_kernel<EMBED, EMBED, false>
      <<<g3, 256, 0, stream>>>(attn_buf, w_out, b_out, out, nullptr, nullptr, nullptr);
}

// Round 3
// 472.806 us; speedup vs baseline: 4.3834x; 1.9609x over previous
//
#include <hip/hip_runtime.h>

#define EMBED 768
#define NH 12
#define HD 64
#define SEQ 4096
#define BATCH 2
#define MROWS (BATCH * SEQ)   // 8192
#define N3E (3 * EMBED)       // 2304

typedef short bf16x8 __attribute__((ext_vector_type(8)));  // 8 bf16 = 4 VGPRs
typedef float fx4 __attribute__((ext_vector_type(4)));     // MFMA C/D
typedef unsigned short ushort_t;

// fp32 -> bf16 round-to-nearest-even
__device__ inline ushort_t f2bf(float f) {
  union { float f; unsigned int u; } x; x.f = f;
  unsigned int r = x.u + 0x7fffu + ((x.u >> 16) & 1u);
  return (ushort_t)(r >> 16);
}

// ---------------------------------------------------------------------------
// x [M,K] fp32 -> bf16, straight copy. 8 elems/thread.
// ---------------------------------------------------------------------------
__global__ __launch_bounds__(256) void convert_x(const float* __restrict__ in,
                                                 ushort_t* __restrict__ out) {
  int i = (blockIdx.x * 256 + threadIdx.x) * 8;
  float4 a = *(const float4*)(in + i);
  float4 b = *(const float4*)(in + i + 4);
  bf16x8 o;
  o[0] = f2bf(a.x); o[1] = f2bf(a.y); o[2] = f2bf(a.z); o[3] = f2bf(a.w);
  o[4] = f2bf(b.x); o[5] = f2bf(b.y); o[6] = f2bf(b.z); o[7] = f2bf(b.w);
  *(bf16x8*)(out + i) = o;
}

// ---------------------------------------------------------------------------
// W [K,N] fp32 -> W^T [N,K] bf16 via 64x64 LDS tile (stride 65: conflict-free)
// ---------------------------------------------------------------------------
__global__ __launch_bounds__(256) void transpose_w(const float* __restrict__ in,
                                                   ushort_t* __restrict__ out,
                                                   int K, int N) {
  __shared__ float t[64][65];
  const int bn = blockIdx.x * 64, bk = blockIdx.y * 64;
  const int c = threadIdx.x & 63, r0 = threadIdx.x >> 6;
#pragma unroll
  for (int rr = 0; rr < 16; ++rr) {
    int row = rr * 4 + r0;
    t[row][c] = in[(size_t)(bk + row) * N + bn + c];
  }
  __syncthreads();
#pragma unroll
  for (int rr = 0; rr < 16; ++rr) {
    int row = rr * 4 + r0;
    out[(size_t)(bn + row) * K + bk + c] = f2bf(t[c][row]);
  }
}

// ---------------------------------------------------------------------------
// bf16 MFMA GEMM (m97 structure): C[M,N] = A[M,K] @ Bt[N,K]^T + bias.
// 128x128 tile, BK=32, 4 waves x (64x64), global_load_lds width-16 staging,
// XOR-swizzled [m][k-slot] LDS layout (lane-contiguous DMA dest, spread banks).
// SCATTER: N==2304 -> q (pre-scaled 1/8, [B,H,S,D]) / k ([B,H,S,D]) /
//          v (transposed [B,H,D,S]) bf16 buffers.  else: fp32 [M,N] out.
// ---------------------------------------------------------------------------
template <int N_, int K_, bool SCATTER>
__global__ __launch_bounds__(256) void gemm_mfma(
    const ushort_t* __restrict__ A, const ushort_t* __restrict__ Bt,
    const float* __restrict__ bias, float* __restrict__ outF,
    ushort_t* __restrict__ oq, ushort_t* __restrict__ ok,
    ushort_t* __restrict__ ov) {
  __shared__ __align__(16) ushort_t As[128 * 32];
  __shared__ __align__(16) ushort_t Bs[128 * 32];
  const int tid = threadIdx.x;
  const int w = tid >> 6, lane = tid & 63;
  const int quad = lane >> 4, ln = lane & 15;
  const int bm = blockIdx.y * 128, bn = blockIdx.x * 128;
  const int wm = (w >> 1) * 64, wn = (w & 1) * 64;

  const int sr = lane >> 2;     // row within 16-row chunk
  const int sslot = lane & 3;   // 16B slot within row

  fx4 acc[4][4] = {};

  for (int k0 = 0; k0 < K_; k0 += 32) {
    __syncthreads();
#pragma unroll
    for (int r = 0; r < 2; ++r) {
      const int c = w + r * 4;        // chunk 0..7 (wave-uniform)
      const int m = c * 16 + sr;      // tile row 0..127
      const int kk = k0 + ((sslot ^ (m & 3)) << 3);
      __builtin_amdgcn_global_load_lds(
          (const __attribute__((address_space(1))) unsigned int*)
              (A + (size_t)(bm + m) * K_ + kk),
          (__attribute__((address_space(3))) unsigned int*)(As + c * 512),
          16, 0, 0);
      __builtin_amdgcn_global_load_lds(
          (const __attribute__((address_space(1))) unsigned int*)
              (Bt + (size_t)(bn + m) * K_ + kk),
          (__attribute__((address_space(3))) unsigned int*)(Bs + c * 512),
          16, 0, 0);
    }
    __syncthreads();

    bf16x8 af[4], bfr[4];
#pragma unroll
    for (int i = 0; i < 4; ++i) {
      const int m = wm + i * 16 + ln;
      af[i] = *(const bf16x8*)(As + m * 32 + ((quad ^ (m & 3)) << 3));
    }
#pragma unroll
    for (int j = 0; j < 4; ++j) {
      const int n = wn + j * 16 + ln;
      bfr[j] = *(const bf16x8*)(Bs + n * 32 + ((quad ^ (n & 3)) << 3));
    }
#pragma unroll
    for (int i = 0; i < 4; ++i)
#pragma unroll
      for (int j = 0; j < 4; ++j)
        acc[i][j] = __builtin_amdgcn_mfma_f32_16x16x32_bf16(af[i], bfr[j],
                                                            acc[i][j], 0, 0, 0);
  }

  if (!SCATTER) {
#pragma unroll
    for (int j = 0; j < 4; ++j) {
      const int n = bn + wn + j * 16 + ln;
      const float bv = bias[n];
#pragma unroll
      for (int i = 0; i < 4; ++i) {
        const int m0 = bm + wm + i * 16 + quad * 4;
#pragma unroll
        for (int r = 0; r < 4; ++r)
          outF[(size_t)(m0 + r) * N_ + n] = acc[i][j][r] + bv;
      }
    }
  } else {
    const int t = bn / EMBED;  // 768 % 128 == 0: whole tile in one of q/k/v
#pragma unroll
    for (int j = 0; j < 4; ++j) {
      const int nn = bn + wn + j * 16 + ln;
      const int rem = nn - t * EMBED;
      const int h = rem >> 6, d = rem & 63;
      const float bv = bias[nn];
#pragma unroll
      for (int i = 0; i < 4; ++i) {
        const int m0 = bm + wm + i * 16 + quad * 4;
#pragma unroll
        for (int r = 0; r < 4; ++r) {
          const int m = m0 + r;
          const int b_ = m >> 12, s = m & 4095;
          const float v = acc[i][j][r] + bv;
          if (t == 0)
            oq[((size_t)(b_ * NH + h) * SEQ + s) * HD + d] = f2bf(v * 0.125f);
          else if (t == 1)
            ok[((size_t)(b_ * NH + h) * SEQ + s) * HD + d] = f2bf(v);
          else
            ov[((size_t)(b_ * NH + h) * HD + d) * SEQ + s] = f2bf(v);
        }
      }
    }
  }
}

// ---------------------------------------------------------------------------
// Causal flash attention, bf16 MFMA (16x16x32), fp32 accumulate.
// V arrives pre-transposed [B,H,D,S] -> Vt staging is a plain coalesced copy.
// Softmax fully in registers (butterfly over 16-lane groups).
// Output written bf16 [B,S,E] (feeds the MFMA out-proj directly).
// ---------------------------------------------------------------------------
__global__ __launch_bounds__(256) void flash_mfma(
    const ushort_t* __restrict__ qb, const ushort_t* __restrict__ kb,
    const ushort_t* __restrict__ vb, ushort_t* __restrict__ attn) {
  __shared__ __align__(16) ushort_t Ks[64][72];  // [kr][d], 144B rows (16B-mult)
  __shared__ __align__(16) ushort_t Vt[64][72];  // [d][kr]
  __shared__ __align__(16) ushort_t Ps[64][72];  // [qr][kr]

  const int tid = threadIdx.x;
  const int w = tid >> 6;
  const int lane = tid & 63;
  const int quad = lane >> 4;
  const int ln = lane & 15;

  const int qt = (int)gridDim.x - 1 - (int)blockIdx.x;  // big blocks first
  const int bh = blockIdx.y;
  const size_t base = (size_t)bh * SEQ * HD;
  const ushort_t* Qg = qb + base;
  const ushort_t* Kg = kb + base;
  const ushort_t* Vg = vb + base;  // [HD][SEQ]

  bf16x8 qf0, qf1;
  {
    const ushort_t* qrow = Qg + (size_t)(qt * 64 + w * 16 + ln) * HD;
    qf0 = *(const bf16x8*)(qrow + quad * 8);
    qf1 = *(const bf16x8*)(qrow + 32 + quad * 8);
  }

  fx4 oacc[4] = {};
  float mrow[4], lrow[4];
#pragma unroll
  for (int r = 0; r < 4; ++r) { mrow[r] = -1e30f; lrow[r] = 0.f; }

  for (int kt = 0; kt <= qt; ++kt) {
    __syncthreads();  // protect previous iteration's LDS reads
#pragma unroll
    for (int r = 0; r < 2; ++r) {
      int c = tid + r * 256;
      int row = c >> 3, c0 = (c & 7) * 8;
      // K tile [kr][d] from [B,H,S,D]
      *(bf16x8*)&Ks[row][c0] =
          *(const bf16x8*)(Kg + (size_t)(kt * 64 + row) * HD + c0);
      // V tile [d][kr] from pre-transposed [B,H,D,S]
      *(bf16x8*)&Vt[row][c0] =
          *(const bf16x8*)(Vg + (size_t)row * SEQ + kt * 64 + c0);
    }
    __syncthreads();

    const bool diag = (kt == qt);
    float sv[4][4];
#pragma unroll
    for (int t = 0; t < 4; ++t) {
      if (diag && t > w) {
#pragma unroll
        for (int r = 0; r < 4; ++r) sv[t][r] = -1e30f;
      } else {
        fx4 c = {};
        bf16x8 kf0 = *(const bf16x8*)&Ks[t * 16 + ln][quad * 8];
        bf16x8 kf1 = *(const bf16x8*)&Ks[t * 16 + ln][32 + quad * 8];
        c = __builtin_amdgcn_mfma_f32_16x16x32_bf16(qf0, kf0, c, 0, 0, 0);
        c = __builtin_amdgcn_mfma_f32_16x16x32_bf16(qf1, kf1, c, 0, 0, 0);
#pragma unroll
        for (int r = 0; r < 4; ++r) sv[t][r] = c[r];
        if (diag && t == w) {
#pragma unroll
          for (int r = 0; r < 4; ++r)
            if (ln > quad * 4 + r) sv[t][r] = -1e30f;
        }
      }
    }

    float mnew[4], alpha[4];
#pragma unroll
    for (int r = 0; r < 4; ++r) {
      float rm = fmaxf(fmaxf(sv[0][r], sv[1][r]), fmaxf(sv[2][r], sv[3][r]));
      rm = fmaxf(rm, __shfl_xor(rm, 1));
      rm = fmaxf(rm, __shfl_xor(rm, 2));
      rm = fmaxf(rm, __shfl_xor(rm, 4));
      rm = fmaxf(rm, __shfl_xor(rm, 8));
      mnew[r] = fmaxf(mrow[r], rm);
      alpha[r] = __expf(mrow[r] - mnew[r]);
      mrow[r] = mnew[r];
    }
    float pv[4][4];
#pragma unroll
    for (int r = 0; r < 4; ++r) {
      float s0 = 0.f;
#pragma unroll
      for (int t = 0; t < 4; ++t) {
        float e = __expf(sv[t][r] - mnew[r]);
        pv[t][r] = e;
        s0 += e;
      }
      s0 += __shfl_xor(s0, 1);
      s0 += __shfl_xor(s0, 2);
      s0 += __shfl_xor(s0, 4);
      s0 += __shfl_xor(s0, 8);
      lrow[r] = lrow[r] * alpha[r] + s0;
    }
#pragma unroll
    for (int t = 0; t < 4; ++t)
#pragma unroll
      for (int r = 0; r < 4; ++r)
        Ps[w * 16 + quad * 4 + r][t * 16 + ln] = f2bf(pv[t][r]);
#pragma unroll
    for (int t = 0; t < 4; ++t)
#pragma unroll
      for (int r = 0; r < 4; ++r) oacc[t][r] *= alpha[r];
#pragma unroll
    for (int kb2 = 0; kb2 < 2; ++kb2) {
      bf16x8 pf = *(const bf16x8*)&Ps[w * 16 + ln][kb2 * 32 + quad * 8];
#pragma unroll
      for (int t = 0; t < 4; ++t) {
        bf16x8 vf = *(const bf16x8*)&Vt[t * 16 + ln][kb2 * 32 + quad * 8];
        oacc[t] = __builtin_amdgcn_mfma_f32_16x16x32_bf16(pf, vf, oacc[t], 0, 0, 0);
      }
    }
  }

  const int b_ = bh / NH, h = bh % NH;
#pragma unroll
  for (int r = 0; r < 4; ++r) {
    float inv = 1.f / lrow[r];
    int srow = qt * 64 + w * 16 + quad * 4 + r;
    ushort_t* orow = attn + ((size_t)(b_ * SEQ + srow)) * EMBED + h * HD;
#pragma unroll
    for (int t = 0; t < 4; ++t) orow[t * 16 + ln] = f2bf(oacc[t][r] * inv);
  }
}

extern "C" void kernel_launch(void* const* d_in, const int* in_sizes, int n_in,
                              void* d_out, int out_size, void* d_ws,
                              size_t ws_size, hipStream_t stream) {
  const float* x = (const float*)d_in[0];      // [B,S,E]
  const float* w_qkv = (const float*)d_in[1];  // [E,3E]
  const float* b_qkv = (const float*)d_in[2];  // [3E]
  const float* w_out = (const float*)d_in[3];  // [E,E]
  const float* b_out = (const float*)d_in[4];  // [E]
  float* out = (float*)d_out;                  // [B,S,E] fp32

  const size_t per = (size_t)BATCH * NH * SEQ * HD;  // 6291456
  ushort_t* q_buf = (ushort_t*)d_ws;          // [B,H,S,D]
  ushort_t* k_buf = q_buf + per;              // [B,H,S,D]
  ushort_t* v_buf = k_buf + per;              // [B,H,D,S] (transposed)
  ushort_t* attn_buf = v_buf + per;           // [B,S,E] bf16
  ushort_t* xb = attn_buf + per;              // [M,E] bf16
  ushort_t* wqkvT = xb + per;                 // [3E,E] bf16
  ushort_t* woutT = wqkvT + (size_t)N3E * EMBED;  // [E,E] bf16

  convert_x<<<(MROWS * EMBED) / 2048, 256, 0, stream>>>(x, xb);
  transpose_w<<<dim3(N3E / 64, EMBED / 64), 256, 0, stream>>>(w_qkv, wqkvT,
                                                              EMBED, N3E);
  transpose_w<<<dim3(EMBED / 64, EMBED / 64), 256, 0, stream>>>(w_out, woutT,
                                                                EMBED, EMBED);

  dim3 g1(N3E / 128, MROWS / 128);  // (18,64)
  gemm_mfma<N3E, EMBED, true><<<g1, 256, 0, stream>>>(
      xb, wqkvT, b_qkv, nullptr, q_buf, k_buf, v_buf);

  dim3 g2(SEQ / 64, BATCH * NH);  // (64,24)
  flash_mfma<<<g2, 256, 0, stream>>>(q_buf, k_buf, v_buf, attn_buf);

  dim3 g3(EMBED / 128, MROWS / 128);  // (6,64)
  gemm_mfma<EMBED, EMBED, false><<<g3, 256, 0, stream>>>(
      attn_buf, woutT, b_out, out, nullptr, nullptr, nullptr);
}

// Round 4
// 299.276 us; speedup vs baseline: 6.9251x; 1.5798x over previous
//
#include <hip/hip_runtime.h>

#define EMBED 768
#define NH 12
#define HD 64
#define SEQ 4096
#define BATCH 2
#define MROWS (BATCH * SEQ)   // 8192
#define N3E (3 * EMBED)       // 2304

typedef short bf16x8 __attribute__((ext_vector_type(8)));  // 8 bf16 = 4 VGPRs
typedef float fx4 __attribute__((ext_vector_type(4)));     // MFMA C/D
typedef unsigned short ushort_t;
typedef unsigned short us4 __attribute__((ext_vector_type(4)));  // 8B packed

// fp32 -> bf16 round-to-nearest-even
__device__ inline ushort_t f2bf(float f) {
  union { float f; unsigned int u; } x; x.f = f;
  unsigned int r = x.u + 0x7fffu + ((x.u >> 16) & 1u);
  return (ushort_t)(r >> 16);
}

// ---------------------------------------------------------------------------
// x [M,K] fp32 -> bf16, straight copy. 8 elems/thread.
// ---------------------------------------------------------------------------
__global__ __launch_bounds__(256) void convert_x(const float* __restrict__ in,
                                                 ushort_t* __restrict__ out) {
  int i = (blockIdx.x * 256 + threadIdx.x) * 8;
  float4 a = *(const float4*)(in + i);
  float4 b = *(const float4*)(in + i + 4);
  bf16x8 o;
  o[0] = f2bf(a.x); o[1] = f2bf(a.y); o[2] = f2bf(a.z); o[3] = f2bf(a.w);
  o[4] = f2bf(b.x); o[5] = f2bf(b.y); o[6] = f2bf(b.z); o[7] = f2bf(b.w);
  *(bf16x8*)(out + i) = o;
}

// ---------------------------------------------------------------------------
// W [K,N] fp32 -> W^T [N,K] bf16 via 64x64 LDS tile (stride 65: conflict-free)
// ---------------------------------------------------------------------------
__global__ __launch_bounds__(256) void transpose_w(const float* __restrict__ in,
                                                   ushort_t* __restrict__ out,
                                                   int K, int N) {
  __shared__ float t[64][65];
  const int bn = blockIdx.x * 64, bk = blockIdx.y * 64;
  const int c = threadIdx.x & 63, r0 = threadIdx.x >> 6;
#pragma unroll
  for (int rr = 0; rr < 16; ++rr) {
    int row = rr * 4 + r0;
    t[row][c] = in[(size_t)(bk + row) * N + bn + c];
  }
  __syncthreads();
#pragma unroll
  for (int rr = 0; rr < 16; ++rr) {
    int row = rr * 4 + r0;
    out[(size_t)(bn + row) * K + bk + c] = f2bf(t[c][row]);
  }
}

// ---------------------------------------------------------------------------
// bf16 MFMA GEMM (m97 structure): C[M,N] = A[M,K] @ Bt[N,K]^T + bias.
// 128x128 tile, BK=32, 4 waves x (64x64), global_load_lds width-16 staging,
// XOR-swizzled [m][k-slot] LDS layout.
// SCATTER: N==2304 -> q (pre-scaled 1/8, [B,H,S,D]) / k ([B,H,S,D]) /
//          v (transposed [B,H,D,S]) bf16 buffers.  else: fp32 [M,N] out.
// ---------------------------------------------------------------------------
template <int N_, int K_, bool SCATTER>
__global__ __launch_bounds__(256) void gemm_mfma(
    const ushort_t* __restrict__ A, const ushort_t* __restrict__ Bt,
    const float* __restrict__ bias, float* __restrict__ outF,
    ushort_t* __restrict__ oq, ushort_t* __restrict__ ok,
    ushort_t* __restrict__ ov) {
  __shared__ __align__(16) ushort_t As[128 * 32];
  __shared__ __align__(16) ushort_t Bs[128 * 32];
  const int tid = threadIdx.x;
  const int w = tid >> 6, lane = tid & 63;
  const int quad = lane >> 4, ln = lane & 15;
  const int bm = blockIdx.y * 128, bn = blockIdx.x * 128;
  const int wm = (w >> 1) * 64, wn = (w & 1) * 64;

  const int sr = lane >> 2;     // row within 16-row chunk
  const int sslot = lane & 3;   // 16B slot within row

  fx4 acc[4][4] = {};

  for (int k0 = 0; k0 < K_; k0 += 32) {
    __syncthreads();
#pragma unroll
    for (int r = 0; r < 2; ++r) {
      const int c = w + r * 4;        // chunk 0..7 (wave-uniform)
      const int m = c * 16 + sr;      // tile row 0..127
      const int kk = k0 + ((sslot ^ (m & 3)) << 3);
      __builtin_amdgcn_global_load_lds(
          (const __attribute__((address_space(1))) unsigned int*)
              (A + (size_t)(bm + m) * K_ + kk),
          (__attribute__((address_space(3))) unsigned int*)(As + c * 512),
          16, 0, 0);
      __builtin_amdgcn_global_load_lds(
          (const __attribute__((address_space(1))) unsigned int*)
              (Bt + (size_t)(bn + m) * K_ + kk),
          (__attribute__((address_space(3))) unsigned int*)(Bs + c * 512),
          16, 0, 0);
    }
    __syncthreads();

    bf16x8 af[4], bfr[4];
#pragma unroll
    for (int i = 0; i < 4; ++i) {
      const int m = wm + i * 16 + ln;
      af[i] = *(const bf16x8*)(As + m * 32 + ((quad ^ (m & 3)) << 3));
    }
#pragma unroll
    for (int j = 0; j < 4; ++j) {
      const int n = wn + j * 16 + ln;
      bfr[j] = *(const bf16x8*)(Bs + n * 32 + ((quad ^ (n & 3)) << 3));
    }
#pragma unroll
    for (int i = 0; i < 4; ++i)
#pragma unroll
      for (int j = 0; j < 4; ++j)
        acc[i][j] = __builtin_amdgcn_mfma_f32_16x16x32_bf16(af[i], bfr[j],
                                                            acc[i][j], 0, 0, 0);
  }

  if (!SCATTER) {
#pragma unroll
    for (int j = 0; j < 4; ++j) {
      const int n = bn + wn + j * 16 + ln;
      const float bv = bias[n];
#pragma unroll
      for (int i = 0; i < 4; ++i) {
        const int m0 = bm + wm + i * 16 + quad * 4;
#pragma unroll
        for (int r = 0; r < 4; ++r)
          outF[(size_t)(m0 + r) * N_ + n] = acc[i][j][r] + bv;
      }
    }
  } else {
    const int t = bn / EMBED;  // 768 % 128 == 0: whole tile in one of q/k/v
#pragma unroll
    for (int j = 0; j < 4; ++j) {
      const int nn = bn + wn + j * 16 + ln;
      const int rem = nn - t * EMBED;
      const int h = rem >> 6, d = rem & 63;
      const float bv = bias[nn];
#pragma unroll
      for (int i = 0; i < 4; ++i) {
        const int m0 = bm + wm + i * 16 + quad * 4;
#pragma unroll
        for (int r = 0; r < 4; ++r) {
          const int m = m0 + r;
          const int b_ = m >> 12, s = m & 4095;
          const float v = acc[i][j][r] + bv;
          if (t == 0)
            oq[((size_t)(b_ * NH + h) * SEQ + s) * HD + d] = f2bf(v * 0.125f);
          else if (t == 1)
            ok[((size_t)(b_ * NH + h) * SEQ + s) * HD + d] = f2bf(v);
          else
            ov[((size_t)(b_ * NH + h) * HD + d) * SEQ + s] = f2bf(v);
        }
      }
    }
  }
}

// ---------------------------------------------------------------------------
// Causal flash attention, bf16 MFMA, fp32 accumulate.
//  * Triangle pairing: block p handles qt = 63-p then qt = p (65 staged
//    iterations per block, perfectly balanced; grid 32 x 24 = 768 blocks,
//    3/CU resident).
//  * S^T trick: QK MFMA as (A=K, B=Q) -> each lane owns ONE q-row (qr=ln):
//    scalar m/l state, 2-shuffle reductions, P writes are 4x ds_write_b64.
//  * K/V staged via global_load_lds(16B), XOR-swizzled source granules
//    (LDS unpadded for DMA; reads stay conflict-free), double-buffered so
//    the kt+1 DMA flies during kt compute.
// ---------------------------------------------------------------------------
__global__ __launch_bounds__(256) void flash_mfma(
    const ushort_t* __restrict__ qb, const ushort_t* __restrict__ kb,
    const ushort_t* __restrict__ vb, ushort_t* __restrict__ attn) {
  __shared__ __align__(16) ushort_t Ks[2][64 * 64];  // [kr][slot] swizzled
  __shared__ __align__(16) ushort_t Vt[2][64 * 64];  // [d][slot] swizzled
  __shared__ __align__(16) ushort_t Ps[64][72];      // [qr][kr], padded

  const int tid = threadIdx.x;
  const int w = tid >> 6;
  const int lane = tid & 63;
  const int quad = lane >> 4;
  const int ln = lane & 15;

  const int p = blockIdx.x;   // pair index 0..31
  const int bh = blockIdx.y;  // 0..23
  const size_t base = (size_t)bh * SEQ * HD;
  const ushort_t* Qg = qb + base;
  const ushort_t* Kg = kb + base;
  const ushort_t* Vg = vb + base;  // [HD][SEQ]

  // staging geometry (kt-invariant): chunk c covers rows c*8+srow; wave w
  // issues chunks {w, w+4}; stored slot s holds logical granule s^(row&7).
  const int srow = lane >> 3;
  const int sg = (lane & 7) ^ srow;  // logical granule this lane fetches

  const int b_ = bh / NH, h = bh % NH;

  for (int phase = 0; phase < 2; ++phase) {
    const int qt = (phase == 0) ? (63 - p) : p;

    bf16x8 qf0, qf1;
    {
      const ushort_t* qrow = Qg + (size_t)(qt * 64 + w * 16 + ln) * HD;
      qf0 = *(const bf16x8*)(qrow + quad * 8);
      qf1 = *(const bf16x8*)(qrow + 32 + quad * 8);
    }
    fx4 oacc[4] = {};
    float m_i = -1e30f, l_i = 0.f;

    __syncthreads();  // previous phase/iteration done reading buf 0
    // prologue: stage kt=0 into buf 0
#pragma unroll
    for (int r2 = 0; r2 < 2; ++r2) {
      const int c = w + r2 * 4;
      const int row = c * 8 + srow;
      __builtin_amdgcn_global_load_lds(
          (const __attribute__((address_space(1))) unsigned int*)
              (Kg + (size_t)row * HD + (sg << 3)),
          (__attribute__((address_space(3))) unsigned int*)(&Ks[0][c * 512]),
          16, 0, 0);
      __builtin_amdgcn_global_load_lds(
          (const __attribute__((address_space(1))) unsigned int*)
              (Vg + (size_t)row * SEQ + (sg << 3)),
          (__attribute__((address_space(3))) unsigned int*)(&Vt[0][c * 512]),
          16, 0, 0);
    }

    for (int kt = 0; kt <= qt; ++kt) {
      const int cur = kt & 1;
      __syncthreads();  // publish buf `cur` (drains in-flight DMA)
      if (kt < qt) {    // prefetch kt+1 into the other buffer
        const int nxt = cur ^ 1;
#pragma unroll
        for (int r2 = 0; r2 < 2; ++r2) {
          const int c = w + r2 * 4;
          const int row = c * 8 + srow;
          __builtin_amdgcn_global_load_lds(
              (const __attribute__((address_space(1))) unsigned int*)
                  (Kg + (size_t)((kt + 1) * 64 + row) * HD + (sg << 3)),
              (__attribute__((address_space(3))) unsigned int*)(&Ks[nxt][c * 512]),
              16, 0, 0);
          __builtin_amdgcn_global_load_lds(
              (const __attribute__((address_space(1))) unsigned int*)
                  (Vg + (size_t)row * SEQ + (kt + 1) * 64 + (sg << 3)),
              (__attribute__((address_space(3))) unsigned int*)(&Vt[nxt][c * 512]),
              16, 0, 0);
        }
      }

      const bool diag = (kt == qt);
      // ---- S^T = K.Q^T : lane owns q-row qr=ln, kr = t*16+quad*4+r ----
      float sv[4][4];
#pragma unroll
      for (int t = 0; t < 4; ++t) {
        if (diag && t > w) {
#pragma unroll
          for (int r = 0; r < 4; ++r) sv[t][r] = -1e30f;
        } else {
          const int R = t * 16 + ln;
          const int off = R * 64 + ((quad ^ (R & 7)) << 3);
          bf16x8 kf0 = *(const bf16x8*)(&Ks[cur][off]);
          bf16x8 kf1 = *(const bf16x8*)(&Ks[cur][off ^ 32]);
          fx4 c = {};
          c = __builtin_amdgcn_mfma_f32_16x16x32_bf16(kf0, qf0, c, 0, 0, 0);
          c = __builtin_amdgcn_mfma_f32_16x16x32_bf16(kf1, qf1, c, 0, 0, 0);
#pragma unroll
          for (int r = 0; r < 4; ++r) sv[t][r] = c[r];
          if (diag && t == w) {
#pragma unroll
            for (int r = 0; r < 4; ++r)
              if (quad * 4 + r > ln) sv[t][r] = -1e30f;
          }
        }
      }

      // ---- online softmax: one q-row per lane, scalar state ----
      float rm = sv[0][0];
#pragma unroll
      for (int t = 0; t < 4; ++t)
#pragma unroll
        for (int r = 0; r < 4; ++r) rm = fmaxf(rm, sv[t][r]);
      rm = fmaxf(rm, __shfl_xor(rm, 16));
      rm = fmaxf(rm, __shfl_xor(rm, 32));
      const float mnew = fmaxf(m_i, rm);
      const float alpha = __expf(m_i - mnew);
      m_i = mnew;

      float s0 = 0.f;
      us4 pk[4];
#pragma unroll
      for (int t = 0; t < 4; ++t)
#pragma unroll
        for (int r = 0; r < 4; ++r) {
          float e = __expf(sv[t][r] - mnew);
          s0 += e;
          union { float f; unsigned int u; } x; x.f = e;
          pk[t][r] = (ushort_t)((x.u + 0x8000u) >> 16);  // half-up round
        }
      s0 += __shfl_xor(s0, 16);
      s0 += __shfl_xor(s0, 32);
      l_i = l_i * alpha + s0;

      // P writes: 4 contiguous bf16 per t -> b64 (wave-private rows)
#pragma unroll
      for (int t = 0; t < 4; ++t)
        *(us4*)&Ps[w * 16 + ln][t * 16 + quad * 4] = pk[t];

      // rescale O (alpha lives at lane qr; O-rows are quad*4+r)
      float alr[4];
#pragma unroll
      for (int r = 0; r < 4; ++r) alr[r] = __shfl(alpha, quad * 4 + r);
#pragma unroll
      for (int t = 0; t < 4; ++t)
#pragma unroll
        for (int r = 0; r < 4; ++r) oacc[t][r] *= alr[r];

      // ---- O += P.V ----
#pragma unroll
      for (int kb2 = 0; kb2 < 2; ++kb2) {
        bf16x8 pf = *(const bf16x8*)&Ps[w * 16 + ln][kb2 * 32 + quad * 8];
#pragma unroll
        for (int t = 0; t < 4; ++t) {
          const int Rv = t * 16 + ln;
          const int offv = Rv * 64 + (((kb2 * 4 + quad) ^ (Rv & 7)) << 3);
          bf16x8 vf = *(const bf16x8*)(&Vt[cur][offv]);
          oacc[t] = __builtin_amdgcn_mfma_f32_16x16x32_bf16(pf, vf, oacc[t],
                                                            0, 0, 0);
        }
      }
    }

    // ---- epilogue: O/l -> attn bf16 [B,S,E] ----
    float lr[4];
#pragma unroll
    for (int r = 0; r < 4; ++r) lr[r] = __shfl(l_i, quad * 4 + r);
#pragma unroll
    for (int r = 0; r < 4; ++r) {
      const float inv = 1.f / lr[r];
      const int srow2 = qt * 64 + w * 16 + quad * 4 + r;
      ushort_t* orow = attn + (size_t)(b_ * SEQ + srow2) * EMBED + h * HD;
#pragma unroll
      for (int t = 0; t < 4; ++t) orow[t * 16 + ln] = f2bf(oacc[t][r] * inv);
    }
  }
}

extern "C" void kernel_launch(void* const* d_in, const int* in_sizes, int n_in,
                              void* d_out, int out_size, void* d_ws,
                              size_t ws_size, hipStream_t stream) {
  const float* x = (const float*)d_in[0];      // [B,S,E]
  const float* w_qkv = (const float*)d_in[1];  // [E,3E]
  const float* b_qkv = (const float*)d_in[2];  // [3E]
  const float* w_out = (const float*)d_in[3];  // [E,E]
  const float* b_out = (const float*)d_in[4];  // [E]
  float* out = (float*)d_out;                  // [B,S,E] fp32

  const size_t per = (size_t)BATCH * NH * SEQ * HD;  // 6291456
  ushort_t* q_buf = (ushort_t*)d_ws;          // [B,H,S,D]
  ushort_t* k_buf = q_buf + per;              // [B,H,S,D]
  ushort_t* v_buf = k_buf + per;              // [B,H,D,S] (transposed)
  ushort_t* attn_buf = v_buf + per;           // [B,S,E] bf16
  ushort_t* xb = attn_buf + per;              // [M,E] bf16
  ushort_t* wqkvT = xb + per;                 // [3E,E] bf16
  ushort_t* woutT = wqkvT + (size_t)N3E * EMBED;  // [E,E] bf16

  convert_x<<<(MROWS * EMBED) / 2048, 256, 0, stream>>>(x, xb);
  transpose_w<<<dim3(N3E / 64, EMBED / 64), 256, 0, stream>>>(w_qkv, wqkvT,
                                                              EMBED, N3E);
  transpose_w<<<dim3(EMBED / 64, EMBED / 64), 256, 0, stream>>>(w_out, woutT,
                                                                EMBED, EMBED);

  dim3 g1(N3E / 128, MROWS / 128);  // (18,64)
  gemm_mfma<N3E, EMBED, true><<<g1, 256, 0, stream>>>(
      xb, wqkvT, b_qkv, nullptr, q_buf, k_buf, v_buf);

  dim3 g2(32, BATCH * NH);  // triangle-paired: 32 x 24
  flash_mfma<<<g2, 256, 0, stream>>>(q_buf, k_buf, v_buf, attn_buf);

  dim3 g3(EMBED / 128, MROWS / 128);  // (6,64)
  gemm_mfma<EMBED, EMBED, false><<<g3, 256, 0, stream>>>(
      attn_buf, woutT, b_out, out, nullptr, nullptr, nullptr);
}

// Round 5
// 284.707 us; speedup vs baseline: 7.2794x; 1.0512x over previous
//
#include <hip/hip_runtime.h>

#define EMBED 768
#define NH 12
#define HD 64
#define SEQ 4096
#define BATCH 2
#define MROWS (BATCH * SEQ)   // 8192
#define N3E (3 * EMBED)       // 2304

typedef short bf16x8 __attribute__((ext_vector_type(8)));  // 8 bf16 = 4 VGPRs
typedef float fx4 __attribute__((ext_vector_type(4)));     // MFMA C/D
typedef unsigned short ushort_t;
typedef unsigned short us4 __attribute__((ext_vector_type(4)));  // 8B packed

#if __has_builtin(__builtin_amdgcn_exp2f)
#define EXP2F(x) __builtin_amdgcn_exp2f(x)
#else
#define EXP2F(x) exp2f(x)
#endif

// Q pre-scale: (1/sqrt(64)) * log2(e)  -> softmax runs in exp2 domain
#define QSCALE 0.18033688011112042f

// fp32 -> bf16 round-to-nearest-even
__device__ inline ushort_t f2bf(float f) {
  union { float f; unsigned int u; } x; x.f = f;
  unsigned int r = x.u + 0x7fffu + ((x.u >> 16) & 1u);
  return (ushort_t)(r >> 16);
}

// ---------------------------------------------------------------------------
// x [M,K] fp32 -> bf16, straight copy. 8 elems/thread.
// ---------------------------------------------------------------------------
__global__ __launch_bounds__(256) void convert_x(const float* __restrict__ in,
                                                 ushort_t* __restrict__ out) {
  int i = (blockIdx.x * 256 + threadIdx.x) * 8;
  float4 a = *(const float4*)(in + i);
  float4 b = *(const float4*)(in + i + 4);
  bf16x8 o;
  o[0] = f2bf(a.x); o[1] = f2bf(a.y); o[2] = f2bf(a.z); o[3] = f2bf(a.w);
  o[4] = f2bf(b.x); o[5] = f2bf(b.y); o[6] = f2bf(b.z); o[7] = f2bf(b.w);
  *(bf16x8*)(out + i) = o;
}

// ---------------------------------------------------------------------------
// W [K,N] fp32 -> W^T [N,K] bf16 via 64x64 LDS tile (stride 65: conflict-free)
// ---------------------------------------------------------------------------
__global__ __launch_bounds__(256) void transpose_w(const float* __restrict__ in,
                                                   ushort_t* __restrict__ out,
                                                   int K, int N) {
  __shared__ float t[64][65];
  const int bn = blockIdx.x * 64, bk = blockIdx.y * 64;
  const int c = threadIdx.x & 63, r0 = threadIdx.x >> 6;
#pragma unroll
  for (int rr = 0; rr < 16; ++rr) {
    int row = rr * 4 + r0;
    t[row][c] = in[(size_t)(bk + row) * N + bn + c];
  }
  __syncthreads();
#pragma unroll
  for (int rr = 0; rr < 16; ++rr) {
    int row = rr * 4 + r0;
    out[(size_t)(bn + row) * K + bk + c] = f2bf(t[c][row]);
  }
}

// ---------------------------------------------------------------------------
// bf16 MFMA GEMM (m97 structure): C[M,N] = A[M,K] @ Bt[N,K]^T + bias.
// 128x128 tile, BK=32, 4 waves x (64x64), global_load_lds width-16 staging,
// XOR-swizzled [m][k-slot] LDS layout.
// SCATTER: N==2304 -> q (pre-scaled QSCALE, [B,H,S,D]) / k ([B,H,S,D]) /
//          v (transposed [B,H,D,S]) bf16 buffers.  else: fp32 [M,N] out.
// ---------------------------------------------------------------------------
template <int N_, int K_, bool SCATTER>
__global__ __launch_bounds__(256) void gemm_mfma(
    const ushort_t* __restrict__ A, const ushort_t* __restrict__ Bt,
    const float* __restrict__ bias, float* __restrict__ outF,
    ushort_t* __restrict__ oq, ushort_t* __restrict__ ok,
    ushort_t* __restrict__ ov) {
  __shared__ __align__(16) ushort_t As[128 * 32];
  __shared__ __align__(16) ushort_t Bs[128 * 32];
  const int tid = threadIdx.x;
  const int w = tid >> 6, lane = tid & 63;
  const int quad = lane >> 4, ln = lane & 15;
  const int bm = blockIdx.y * 128, bn = blockIdx.x * 128;
  const int wm = (w >> 1) * 64, wn = (w & 1) * 64;

  const int sr = lane >> 2;     // row within 16-row chunk
  const int sslot = lane & 3;   // 16B slot within row

  fx4 acc[4][4] = {};

  for (int k0 = 0; k0 < K_; k0 += 32) {
    __syncthreads();
#pragma unroll
    for (int r = 0; r < 2; ++r) {
      const int c = w + r * 4;        // chunk 0..7 (wave-uniform)
      const int m = c * 16 + sr;      // tile row 0..127
      const int kk = k0 + ((sslot ^ (m & 3)) << 3);
      __builtin_amdgcn_global_load_lds(
          (const __attribute__((address_space(1))) unsigned int*)
              (A + (size_t)(bm + m) * K_ + kk),
          (__attribute__((address_space(3))) unsigned int*)(As + c * 512),
          16, 0, 0);
      __builtin_amdgcn_global_load_lds(
          (const __attribute__((address_space(1))) unsigned int*)
              (Bt + (size_t)(bn + m) * K_ + kk),
          (__attribute__((address_space(3))) unsigned int*)(Bs + c * 512),
          16, 0, 0);
    }
    __syncthreads();

    bf16x8 af[4], bfr[4];
#pragma unroll
    for (int i = 0; i < 4; ++i) {
      const int m = wm + i * 16 + ln;
      af[i] = *(const bf16x8*)(As + m * 32 + ((quad ^ (m & 3)) << 3));
    }
#pragma unroll
    for (int j = 0; j < 4; ++j) {
      const int n = wn + j * 16 + ln;
      bfr[j] = *(const bf16x8*)(Bs + n * 32 + ((quad ^ (n & 3)) << 3));
    }
#pragma unroll
    for (int i = 0; i < 4; ++i)
#pragma unroll
      for (int j = 0; j < 4; ++j)
        acc[i][j] = __builtin_amdgcn_mfma_f32_16x16x32_bf16(af[i], bfr[j],
                                                            acc[i][j], 0, 0, 0);
  }

  if (!SCATTER) {
#pragma unroll
    for (int j = 0; j < 4; ++j) {
      const int n = bn + wn + j * 16 + ln;
      const float bv = bias[n];
#pragma unroll
      for (int i = 0; i < 4; ++i) {
        const int m0 = bm + wm + i * 16 + quad * 4;
#pragma unroll
        for (int r = 0; r < 4; ++r)
          outF[(size_t)(m0 + r) * N_ + n] = acc[i][j][r] + bv;
      }
    }
  } else {
    const int t = bn / EMBED;  // 768 % 128 == 0: whole tile in one of q/k/v
#pragma unroll
    for (int j = 0; j < 4; ++j) {
      const int nn = bn + wn + j * 16 + ln;
      const int rem = nn - t * EMBED;
      const int h = rem >> 6, d = rem & 63;
      const float bv = bias[nn];
#pragma unroll
      for (int i = 0; i < 4; ++i) {
        const int m0 = bm + wm + i * 16 + quad * 4;
#pragma unroll
        for (int r = 0; r < 4; ++r) {
          const int m = m0 + r;
          const int b_ = m >> 12, s = m & 4095;
          const float v = acc[i][j][r] + bv;
          if (t == 0)
            oq[((size_t)(b_ * NH + h) * SEQ + s) * HD + d] = f2bf(v * QSCALE);
          else if (t == 1)
            ok[((size_t)(b_ * NH + h) * SEQ + s) * HD + d] = f2bf(v);
          else
            ov[((size_t)(b_ * NH + h) * HD + d) * SEQ + s] = f2bf(v);
        }
      }
    }
  }
}

// ---------------------------------------------------------------------------
// Causal flash attention, bf16 MFMA, fp32 accumulate.
//  * Triangle pairing: block p handles qt = 63-p then qt = p.
//  * S^T trick (A=K, B=Q): lane owns ONE q-row (qr = ln & 15).
//  * PV operand-swap (A=V^T, B=P): O accumulates as O^T with col=qr=lane ->
//    alpha rescale and 1/l are lane-local scalars (no cross-lane traffic).
//  * exp2-domain softmax (log2e folded into Q scale): raw v_exp_f32.
//  * P packed to bf16 via +0x8000 and v_perm pair-merge; 8B LDS writes.
//  * K/V double-buffered via global_load_lds(16B), XOR-swizzled granules.
// ---------------------------------------------------------------------------
__global__ __launch_bounds__(256, 3) void flash_mfma(
    const ushort_t* __restrict__ qb, const ushort_t* __restrict__ kb,
    const ushort_t* __restrict__ vb, ushort_t* __restrict__ attn) {
  __shared__ __align__(16) ushort_t Ks[2][64 * 64];  // [kr][slot] swizzled
  __shared__ __align__(16) ushort_t Vt[2][64 * 64];  // [d][slot] swizzled
  __shared__ __align__(16) ushort_t Ps[64][72];      // [qr][kr], padded

  const int tid = threadIdx.x;
  const int w = tid >> 6;
  const int lane = tid & 63;
  const int quad = lane >> 4;
  const int ln = lane & 15;

  const int p = blockIdx.x;   // pair index 0..31
  const int bh = blockIdx.y;  // 0..23
  const size_t base = (size_t)bh * SEQ * HD;
  const ushort_t* Qg = qb + base;
  const ushort_t* Kg = kb + base;
  const ushort_t* Vg = vb + base;  // [HD][SEQ]

  // staging geometry: chunk c covers rows c*8+srow; wave w issues chunks
  // {w, w+4}; stored slot s holds logical granule s^(row&7).
  const int srow = lane >> 3;
  const int sg = (lane & 7) ^ srow;

  const int b_ = bh / NH, h = bh % NH;

  for (int phase = 0; phase < 2; ++phase) {
    const int qt = (phase == 0) ? (63 - p) : p;

    bf16x8 qf0, qf1;
    {
      const ushort_t* qrow = Qg + (size_t)(qt * 64 + w * 16 + ln) * HD;
      qf0 = *(const bf16x8*)(qrow + quad * 8);
      qf1 = *(const bf16x8*)(qrow + 32 + quad * 8);
    }
    fx4 oacc[4] = {};  // O^T: col = qr = ln (lane-local), row = d
    float m_i = -1e30f, l_i = 0.f;

    __syncthreads();  // previous phase done reading buf 0
#pragma unroll
    for (int r2 = 0; r2 < 2; ++r2) {
      const int c = w + r2 * 4;
      const int row = c * 8 + srow;
      __builtin_amdgcn_global_load_lds(
          (const __attribute__((address_space(1))) unsigned int*)
              (Kg + (size_t)row * HD + (sg << 3)),
          (__attribute__((address_space(3))) unsigned int*)(&Ks[0][c * 512]),
          16, 0, 0);
      __builtin_amdgcn_global_load_lds(
          (const __attribute__((address_space(1))) unsigned int*)
              (Vg + (size_t)row * SEQ + (sg << 3)),
          (__attribute__((address_space(3))) unsigned int*)(&Vt[0][c * 512]),
          16, 0, 0);
    }

    for (int kt = 0; kt <= qt; ++kt) {
      const int cur = kt & 1;
      __syncthreads();  // publish buf `cur` (drains in-flight DMA)
      if (kt < qt) {    // prefetch kt+1 into the other buffer
        const int nxt = cur ^ 1;
#pragma unroll
        for (int r2 = 0; r2 < 2; ++r2) {
          const int c = w + r2 * 4;
          const int row = c * 8 + srow;
          __builtin_amdgcn_global_load_lds(
              (const __attribute__((address_space(1))) unsigned int*)
                  (Kg + (size_t)((kt + 1) * 64 + row) * HD + (sg << 3)),
              (__attribute__((address_space(3))) unsigned int*)(&Ks[nxt][c * 512]),
              16, 0, 0);
          __builtin_amdgcn_global_load_lds(
              (const __attribute__((address_space(1))) unsigned int*)
                  (Vg + (size_t)row * SEQ + (kt + 1) * 64 + (sg << 3)),
              (__attribute__((address_space(3))) unsigned int*)(&Vt[nxt][c * 512]),
              16, 0, 0);
        }
      }

      const bool diag = (kt == qt);
      // ---- S^T = K.Q^T : lane owns q-row qr=ln; kr = t*16+quad*4+r ----
      float sv[4][4];
#pragma unroll
      for (int t = 0; t < 4; ++t) {
        if (diag && t > w) {
#pragma unroll
          for (int r = 0; r < 4; ++r) sv[t][r] = -1e30f;
        } else {
          const int R = t * 16 + ln;
          const int off = R * 64 + ((quad ^ (R & 7)) << 3);
          bf16x8 kf0 = *(const bf16x8*)(&Ks[cur][off]);
          bf16x8 kf1 = *(const bf16x8*)(&Ks[cur][off ^ 32]);
          fx4 c = {};
          c = __builtin_amdgcn_mfma_f32_16x16x32_bf16(kf0, qf0, c, 0, 0, 0);
          c = __builtin_amdgcn_mfma_f32_16x16x32_bf16(kf1, qf1, c, 0, 0, 0);
#pragma unroll
          for (int r = 0; r < 4; ++r) sv[t][r] = c[r];
          if (diag && t == w) {
#pragma unroll
            for (int r = 0; r < 4; ++r)
              if (quad * 4 + r > ln) sv[t][r] = -1e30f;
          }
        }
      }

      // ---- online softmax (exp2 domain), scalar per-lane state ----
      float rm = sv[0][0];
#pragma unroll
      for (int t = 0; t < 4; ++t)
#pragma unroll
        for (int r = 0; r < 4; ++r) rm = fmaxf(rm, sv[t][r]);
      rm = fmaxf(rm, __shfl_xor(rm, 16));
      rm = fmaxf(rm, __shfl_xor(rm, 32));
      const float mnew = fmaxf(m_i, rm);
      const float alpha = EXP2F(m_i - mnew);
      m_i = mnew;

      float s0 = 0.f;
#pragma unroll
      for (int t = 0; t < 4; ++t) {
        unsigned int u[4];
#pragma unroll
        for (int r = 0; r < 4; ++r) {
          float e = EXP2F(sv[t][r] - mnew);
          s0 += e;
          union { float f; unsigned int u; } x; x.f = e;
          u[r] = x.u + 0x8000u;  // half-up round to bf16
        }
        uint2 pr;
        pr.x = __builtin_amdgcn_perm(u[1], u[0], 0x07060302u);
        pr.y = __builtin_amdgcn_perm(u[3], u[2], 0x07060302u);
        *(uint2*)&Ps[w * 16 + ln][t * 16 + quad * 4] = pr;
      }
      s0 += __shfl_xor(s0, 16);
      s0 += __shfl_xor(s0, 32);
      l_i = l_i * alpha + s0;

      // rescale O^T (alpha lane-local!)
#pragma unroll
      for (int t = 0; t < 4; ++t)
#pragma unroll
        for (int r = 0; r < 4; ++r) oacc[t][r] *= alpha;

      // ---- O^T += V^T.P : mfma(A=vf, B=pf) -> col = qr = ln ----
#pragma unroll
      for (int kb2 = 0; kb2 < 2; ++kb2) {
        bf16x8 pf = *(const bf16x8*)&Ps[w * 16 + ln][kb2 * 32 + quad * 8];
#pragma unroll
        for (int t = 0; t < 4; ++t) {
          const int Rv = t * 16 + ln;
          const int offv = Rv * 64 + (((kb2 * 4 + quad) ^ (Rv & 7)) << 3);
          bf16x8 vf = *(const bf16x8*)(&Vt[cur][offv]);
          oacc[t] = __builtin_amdgcn_mfma_f32_16x16x32_bf16(vf, pf, oacc[t],
                                                            0, 0, 0);
        }
      }
    }

    // ---- epilogue: O^T/l -> attn bf16 [B,S,E]; lane owns q-row ln ----
    const float inv = 1.f / l_i;
    ushort_t* orow =
        attn + (size_t)(b_ * SEQ + qt * 64 + w * 16 + ln) * EMBED + h * HD;
#pragma unroll
    for (int t = 0; t < 4; ++t) {
      us4 o;
#pragma unroll
      for (int r = 0; r < 4; ++r) o[r] = f2bf(oacc[t][r] * inv);
      *(us4*)(orow + t * 16 + quad * 4) = o;
    }
  }
}

extern "C" void kernel_launch(void* const* d_in, const int* in_sizes, int n_in,
                              void* d_out, int out_size, void* d_ws,
                              size_t ws_size, hipStream_t stream) {
  const float* x = (const float*)d_in[0];      // [B,S,E]
  const float* w_qkv = (const float*)d_in[1];  // [E,3E]
  const float* b_qkv = (const float*)d_in[2];  // [3E]
  const float* w_out = (const float*)d_in[3];  // [E,E]
  const float* b_out = (const float*)d_in[4];  // [E]
  float* out = (float*)d_out;                  // [B,S,E] fp32

  const size_t per = (size_t)BATCH * NH * SEQ * HD;  // 6291456
  ushort_t* q_buf = (ushort_t*)d_ws;          // [B,H,S,D] (scaled by QSCALE)
  ushort_t* k_buf = q_buf + per;              // [B,H,S,D]
  ushort_t* v_buf = k_buf + per;              // [B,H,D,S] (transposed)
  ushort_t* attn_buf = v_buf + per;           // [B,S,E] bf16
  ushort_t* xb = attn_buf + per;              // [M,E] bf16
  ushort_t* wqkvT = xb + per;                 // [3E,E] bf16
  ushort_t* woutT = wqkvT + (size_t)N3E * EMBED;  // [E,E] bf16

  convert_x<<<(MROWS * EMBED) / 2048, 256, 0, stream>>>(x, xb);
  transpose_w<<<dim3(N3E / 64, EMBED / 64), 256, 0, stream>>>(w_qkv, wqkvT,
                                                              EMBED, N3E);
  transpose_w<<<dim3(EMBED / 64, EMBED / 64), 256, 0, stream>>>(w_out, woutT,
                                                                EMBED, EMBED);

  dim3 g1(N3E / 128, MROWS / 128);  // (18,64)
  gemm_mfma<N3E, EMBED, true><<<g1, 256, 0, stream>>>(
      xb, wqkvT, b_qkv, nullptr, q_buf, k_buf, v_buf);

  dim3 g2(32, BATCH * NH);  // triangle-paired: 32 x 24
  flash_mfma<<<g2, 256, 0, stream>>>(q_buf, k_buf, v_buf, attn_buf);

  dim3 g3(EMBED / 128, MROWS / 128);  // (6,64)
  gemm_mfma<EMBED, EMBED, false><<<g3, 256, 0, stream>>>(
      attn_buf, woutT, b_out, out, nullptr, nullptr, nullptr);
}